// Round 15
// baseline (86.124 us; speedup 1.0000x reference)
//
#include <hip/hip_runtime.h>
#include <math.h>

#define N_NODES 50000
#define N_EDGES 800000
#define IN_DIM 256
#define OUT_DIM 128
#define ALPHA 0.2f

#define BKT 196              // coarse buckets: dst>>8
#define EPB 4096             // edges per hist/scatter block (512 thr * 8)
#define HIST_NB 196          // 196*4096 >= 800000
#define GEMM_NB 391          // ceil(50000/128), 8 waves, 16 rows/wave

typedef __attribute__((ext_vector_type(8))) short short8;
typedef __attribute__((ext_vector_type(4))) float f32x4;

// ---------------- workspace layout (bytes) ----------------
#define OFF_ZB    0u          // z bf16: 12,800,000
#define OFF_S1    12800000u
#define OFF_S2    13000000u
#define OFF_OFFS2 13200000u   // 50001 ints
#define OFF_WT    13400064u   // 65,536
#define OFF_HIST  13465600u   // histT[bkt][block]: 196*196*4 = 153,664
#define OFF_TMP   13619264u   // u32 packed edges: 3,200,000
#define OFF_SRCS  16819264u   // u16: 1,600,000
// total ~18.4 MB

static __device__ __forceinline__ unsigned short f2bf_rne(float f) {
    unsigned int u = __float_as_uint(f);
    unsigned int r = (u + 0x7FFFu + ((u >> 16) & 1u)) >> 16;
    return (unsigned short)r;
}
static __device__ __forceinline__ unsigned int pack2bf(float lo, float hi) {
    return (unsigned int)f2bf_rne(lo) | ((unsigned int)f2bf_rne(hi) << 16);
}

// ---------------- L0: WT[c][k] = bf16(W[k][c]) ----------------
__global__ __launch_bounds__(256) void wt_k(const float* __restrict__ W,
                                            unsigned short* __restrict__ WT) {
    int idx = (blockIdx.x * 256 + threadIdx.x) * 8;
    int c = idx >> 8, k0 = idx & 255;
    unsigned int uu[4];
#pragma unroll
    for (int q = 0; q < 4; q++) {
        float lo = W[(size_t)(k0 + 2 * q) * OUT_DIM + c];
        float hi = W[(size_t)(k0 + 2 * q + 1) * OUT_DIM + c];
        uu[q] = pack2bf(lo, hi);
    }
    *(uint4*)(WT + idx) = make_uint4(uu[0], uu[1], uu[2], uu[3]);
}

// ---------------- L1: GEMM (32KB LDS, two-phase B) | bucket histogram ----------------
__global__ __launch_bounds__(512) void gemm_hist(const float* __restrict__ h,
                                                 const unsigned short* __restrict__ WT,
                                                 const float* __restrict__ attn,
                                                 unsigned short* __restrict__ zb,
                                                 float* __restrict__ s1,
                                                 float* __restrict__ s2,
                                                 const int* __restrict__ dst,
                                                 int* __restrict__ histT) {
    __shared__ char smem[32768];
    const int t = threadIdx.x;

    if (blockIdx.x >= GEMM_NB) {       // ---- histogram path (LDS atomics only) ----
        int hb = blockIdx.x - GEMM_NB;
        int* hcnt = (int*)smem;
        for (int i = t; i < BKT; i += 512) hcnt[i] = 0;
        __syncthreads();
#pragma unroll
        for (int q = 0; q < 8; q++) {
            int e = hb * EPB + q * 512 + t;
            if (e < N_EDGES) atomicAdd(&hcnt[dst[e] >> 8], 1);
        }
        __syncthreads();
        for (int i = t; i < BKT; i += 512) histT[i * HIST_NB + hb] = hcnt[i];
        return;
    }

    // ---- GEMM path (unchanged) ----
    const int lane = t & 63, w = t >> 6;
    const int row0 = blockIdx.x * 128;
    const int m16 = lane & 15, kb = lane >> 4;

    const int rA = row0 + w * 16 + m16;
    const float* hrow = h + (size_t)min(rA, N_NODES - 1) * IN_DIM + kb * 8;

    f32x4 acc[8];
#pragma unroll
    for (int ct = 0; ct < 8; ct++) acc[ct] = (f32x4){0.f, 0.f, 0.f, 0.f};

    float4 v0 = *(const float4*)(hrow);
    float4 v1 = *(const float4*)(hrow + 4);

#pragma unroll
    for (int half = 0; half < 2; half++) {
        if (half) __syncthreads();
#pragma unroll
        for (int q = 0; q < 4; q++) {
            int G = t * 4 + q;
            int cc = G >> 4, gs = G & 15;
            const uint4 v = *(const uint4*)(WT + (size_t)cc * IN_DIM + half * 128 + gs * 8);
            *(uint4*)(smem + cc * 256 + ((gs ^ (cc & 7)) * 16)) = v;
        }
        __syncthreads();
#pragma unroll
        for (int kcl = 0; kcl < 4; kcl++) {
            const float4 c0 = v0, c1 = v1;
            int nk = half * 4 + kcl + 1;
            if (nk < 8) {
                v0 = *(const float4*)(hrow + nk * 32);
                v1 = *(const float4*)(hrow + nk * 32 + 4);
            }
            short8 af;
            af[0] = (short)f2bf_rne(c0.x); af[1] = (short)f2bf_rne(c0.y);
            af[2] = (short)f2bf_rne(c0.z); af[3] = (short)f2bf_rne(c0.w);
            af[4] = (short)f2bf_rne(c1.x); af[5] = (short)f2bf_rne(c1.y);
            af[6] = (short)f2bf_rne(c1.z); af[7] = (short)f2bf_rne(c1.w);
            const char* bbase = smem + m16 * 256 + (((kcl * 4 + kb) ^ (m16 & 7)) * 16);
#pragma unroll
            for (int ct = 0; ct < 8; ct++) {
                const short8 bf = *(const short8*)(bbase + ct * 4096);
                acc[ct] = __builtin_amdgcn_mfma_f32_16x16x32_bf16(af, bf, acc[ct], 0, 0, 0);
            }
        }
    }

    float a1v[8], a2v[8];
#pragma unroll
    for (int ct = 0; ct < 8; ct++) {
        a1v[ct] = attn[ct * 16 + m16];
        a2v[ct] = attn[OUT_DIM + ct * 16 + m16];
    }
#pragma unroll
    for (int i = 0; i < 4; i++) {
        int rr = row0 + w * 16 + kb * 4 + i;
        float q1 = 0.f, q2 = 0.f;
#pragma unroll
        for (int ct = 0; ct < 8; ct++) {
            q1 += acc[ct][i] * a1v[ct];
            q2 += acc[ct][i] * a2v[ct];
        }
        q1 += __shfl_xor(q1, 1); q1 += __shfl_xor(q1, 2);
        q1 += __shfl_xor(q1, 4); q1 += __shfl_xor(q1, 8);
        q2 += __shfl_xor(q2, 1); q2 += __shfl_xor(q2, 2);
        q2 += __shfl_xor(q2, 4); q2 += __shfl_xor(q2, 8);
        if (m16 == 0 && rr < N_NODES) { s1[rr] = q1; s2[rr] = q2; }
        if (rr < N_NODES) {
#pragma unroll
            for (int ct = 0; ct < 8; ct++)
                zb[(size_t)rr * OUT_DIM + ct * 16 + m16] = f2bf_rne(acc[ct][i]);
        }
    }
}

// ---------------- L2: scatter into bucketed tmp (self-computed prefixes) ----------------
__global__ __launch_bounds__(512) void scatter_b(const int* __restrict__ src,
                                                 const int* __restrict__ dst,
                                                 const int* __restrict__ histT,
                                                 unsigned int* __restrict__ tmp) {
    __shared__ int sS[256];
    __shared__ int bbL[BKT];
    __shared__ int bstartL[BKT];
    __shared__ int cur[BKT];
    int t = threadIdx.x, m = blockIdx.x;

    int tot = 0, bb = 0;
    if (t < BKT) {
        const int* row = histT + t * HIST_NB;
        for (int m2 = 0; m2 < BKT; m2++) {
            int v = row[m2];
            tot += v;
            bb += (m2 < m) ? v : 0;
        }
        bbL[t] = bb;
        cur[t] = 0;
    }
    int d0 = (t < BKT) ? tot : 0;
    if (t < 256) sS[t] = d0;
    __syncthreads();
    int v = d0;
    for (int ofs = 1; ofs < 256; ofs <<= 1) {
        int add = (t < 256 && t >= ofs) ? sS[t - ofs] : 0;
        __syncthreads();
        if (t < 256) { v += add; sS[t] = v; }
        __syncthreads();
    }
    if (t < BKT) bstartL[t] = v - d0;
    __syncthreads();

#pragma unroll
    for (int q = 0; q < 8; q++) {
        int e = m * EPB + q * 512 + t;
        if (e < N_EDGES) {
            int d = dst[e];
            int bkt = d >> 8;
            int r = atomicAdd(&cur[bkt], 1);
            tmp[bstartL[bkt] + bbL[bkt] + r] =
                ((unsigned int)d << 16) | (unsigned int)src[e];
        }
    }
}

// ---------------- L3: per-bucket counting sort -> srcs (u16) + offs2 ----------------
__global__ __launch_bounds__(512) void bucket_sort(const unsigned int* __restrict__ tmp,
                                                   const int* __restrict__ histT,
                                                   unsigned short* __restrict__ srcs,
                                                   int* __restrict__ offs2) {
    __shared__ int sS[256];
    __shared__ int cnt[256];
    __shared__ int cur[256];
    __shared__ int msS, mcS;
    int t = threadIdx.x, b = blockIdx.x;

    int tot = 0;
    if (t < BKT) {
        const int* row = histT + t * HIST_NB;
        for (int m2 = 0; m2 < BKT; m2++) tot += row[m2];
    }
    int d0 = (t < BKT) ? tot : 0;
    if (t < 256) { sS[t] = d0; cnt[t] = 0; }
    __syncthreads();
    int v = d0;
    for (int ofs = 1; ofs < 256; ofs <<= 1) {
        int add = (t < 256 && t >= ofs) ? sS[t - ofs] : 0;
        __syncthreads();
        if (t < 256) { v += add; sS[t] = v; }
        __syncthreads();
    }
    if (t == b) { msS = v - d0; mcS = d0; }     // bucket b's start & count
    __syncthreads();
    const int myStart = msS, myCount = mcS;

    // sweep 1: per-node counts within bucket
    for (int i = t; i < myCount; i += 512)
        atomicAdd(&cnt[(tmp[myStart + i] >> 16) & 255], 1);
    __syncthreads();

    // exclusive scan of cnt[256] (reuse sS)
    int c0 = 0;
    if (t < 256) { c0 = cnt[t]; sS[t] = c0; }
    __syncthreads();
    int cv = c0;
    for (int ofs = 1; ofs < 256; ofs <<= 1) {
        int add = (t < 256 && t >= ofs) ? sS[t - ofs] : 0;
        __syncthreads();
        if (t < 256) { cv += add; sS[t] = cv; }
        __syncthreads();
    }
    if (t < 256) {
        int excl = cv - c0;
        int node = b * 256 + t;
        if (node < N_NODES) offs2[node] = myStart + excl;
        cur[t] = excl;
    }
    if (b == 0 && t == 0) offs2[N_NODES] = N_EDGES;
    __syncthreads();

    // sweep 2: place src payloads
    for (int i = t; i < myCount; i += 512) {
        unsigned int u = tmp[myStart + i];
        int r = atomicAdd(&cur[(u >> 16) & 255], 1);
        srcs[myStart + r] = (unsigned short)(u & 0xFFFFu);
    }
}

// ---------------- L4: softmax + gather-sum (lane = feature-pair, readlane bcast) ----------------
// R14 lesson: per-node fixed cost (48-shfl acc reduction) dominated at avg degree 16.
// New: each lane owns feats {2l, 2l+1} across ALL edges -> no acc reduction at all.
// Edge (ex, src) broadcast via v_readlane (uniform j) -> scalar row base, one
// coalesced 4B/lane load per edge (256 B/wave).
__global__ __launch_bounds__(256) void aggregate(const unsigned short* __restrict__ zb,
                                                 const int* __restrict__ offs2,
                                                 const unsigned short* __restrict__ srcs,
                                                 const float* __restrict__ s1,
                                                 const float* __restrict__ s2,
                                                 float* __restrict__ out) {
    int wid = (blockIdx.x * blockDim.x + threadIdx.x) >> 6;
    int lane = threadIdx.x & 63;
    if (wid >= N_NODES) return;
    float2* outp = (float2*)(out + (size_t)wid * OUT_DIM) + lane;

    int base = offs2[wid];
    int len = offs2[wid + 1] - base;
    if (len == 0) {
        *outp = make_float2(0.f, 0.f);
        return;
    }
    const float s2v = s2[wid];
    const unsigned int voff = lane * 2;      // ushort offset within a z row

    float sum = 0.f;
    float ax = 0.f, ay = 0.f;

    for (int c0 = 0; c0 < len; c0 += 64) {
        int i = c0 + lane;
        float ex = 0.f;
        int sj = 0;
        if (i < len) {
            sj = srcs[base + i];
            float lg = s1[sj] + s2v;
            lg = (lg >= 0.f) ? lg : ALPHA * lg;
            ex = __expf(lg);
        }
        sum += ex;
        int cnt = min(64, len - c0);
        int j = 0;
        for (; j + 4 <= cnt; j += 4) {
#pragma unroll
            for (int q = 0; q < 4; q++) {
                int s = __builtin_amdgcn_readlane(sj, j + q);
                float wj = __int_as_float(__builtin_amdgcn_readlane(__float_as_int(ex), j + q));
                unsigned int u = *(const unsigned int*)(zb + (size_t)(unsigned)s * OUT_DIM + voff);
                ax += wj * __uint_as_float(u << 16);
                ay += wj * __uint_as_float(u & 0xFFFF0000u);
            }
        }
        for (; j < cnt; j++) {
            int s = __builtin_amdgcn_readlane(sj, j);
            float wj = __int_as_float(__builtin_amdgcn_readlane(__float_as_int(ex), j));
            unsigned int u = *(const unsigned int*)(zb + (size_t)(unsigned)s * OUT_DIM + voff);
            ax += wj * __uint_as_float(u << 16);
            ay += wj * __uint_as_float(u & 0xFFFF0000u);
        }
    }
#pragma unroll
    for (int m = 32; m >= 1; m >>= 1) sum += __shfl_xor(sum, m);
    float inv = (sum > 0.f) ? 1.f / sum : 1.f;

    float a0 = ax * inv, a1 = ay * inv;
    float2 o;
    o.x = (a0 > 0.f) ? a0 : expm1f(a0);
    o.y = (a1 > 0.f) ? a1 : expm1f(a1);
    *outp = o;
}

// ---------------- launcher ----------------
extern "C" void kernel_launch(void* const* d_in, const int* in_sizes, int n_in,
                              void* d_out, int out_size, void* d_ws, size_t ws_size,
                              hipStream_t stream) {
    const float* h      = (const float*)d_in[0];
    const int*   src    = (const int*)d_in[1];
    const int*   dst    = (const int*)d_in[2];
    const float* W_fc   = (const float*)d_in[3];
    const float* attn_w = (const float*)d_in[4];
    float* out = (float*)d_out;

    char* ws = (char*)d_ws;
    unsigned short* zb = (unsigned short*)(ws + OFF_ZB);
    float* s1       = (float*)(ws + OFF_S1);
    float* s2       = (float*)(ws + OFF_S2);
    int*   offs2    = (int*)(ws + OFF_OFFS2);
    unsigned short* WT = (unsigned short*)(ws + OFF_WT);
    int*   histT    = (int*)(ws + OFF_HIST);
    unsigned int* tmp = (unsigned int*)(ws + OFF_TMP);
    unsigned short* srcs = (unsigned short*)(ws + OFF_SRCS);

    wt_k<<<16, 256, 0, stream>>>(W_fc, WT);
    gemm_hist<<<GEMM_NB + HIST_NB, 512, 0, stream>>>(h, WT, attn_w, zb, s1, s2, dst, histT);
    scatter_b<<<HIST_NB, 512, 0, stream>>>(src, dst, histT, tmp);
    bucket_sort<<<BKT, 512, 0, stream>>>(tmp, histT, srcs, offs2);
    aggregate<<<(N_NODES * 64) / 256, 256, 0, stream>>>(zb, offs2, srcs, s1, s2, out);
}

// Round 16
// 77.198 us; speedup vs baseline: 1.1156x; 1.1156x over previous
//
#include <hip/hip_runtime.h>
#include <math.h>

#define N_NODES 50000
#define N_EDGES 800000
#define IN_DIM 256
#define OUT_DIM 128
#define ALPHA 0.2f

#define BKT 196              // coarse buckets: dst>>8
#define EPB 4096             // edges per hist/scatter block (512 thr * 8)
#define HIST_NB 196          // 196*4096 >= 800000
#define WT_NB   8            // 8*512*8 u16 = 32768
#define GEMM_NB 391          // ceil(50000/128), 8 waves, 16 rows/wave

typedef __attribute__((ext_vector_type(8))) short short8;
typedef __attribute__((ext_vector_type(4))) float f32x4;

// ---------------- workspace layout (bytes) ----------------
#define OFF_ZB     0u          // z bf16: 12,800,000
#define OFF_S1     12800000u
#define OFF_S2     13000000u
#define OFF_OFFS2  13200000u   // 50001 ints
#define OFF_WT     13400064u   // 65,536
#define OFF_HIST   13465600u   // histT[bkt][block]: 196*196*4 = 153,664
#define OFF_BSTART 13619264u   // 196*4 = 784
#define OFF_BCNT   13620048u   // 784
#define OFF_TMP    13620832u   // u32 packed edges: 3,200,000
#define OFF_SRCS   16820832u   // u16: 1,600,000
// total ~18.4 MB

static __device__ __forceinline__ unsigned short f2bf_rne(float f) {
    unsigned int u = __float_as_uint(f);
    unsigned int r = (u + 0x7FFFu + ((u >> 16) & 1u)) >> 16;
    return (unsigned short)r;
}
static __device__ __forceinline__ unsigned int pack2bf(float lo, float hi) {
    return (unsigned int)f2bf_rne(lo) | ((unsigned int)f2bf_rne(hi) << 16);
}

// ---------------- L0: bucket histogram | WT transpose ----------------
__global__ __launch_bounds__(512) void hist_wt(const int* __restrict__ dst,
                                               const float* __restrict__ W,
                                               int* __restrict__ histT,
                                               unsigned short* __restrict__ WT) {
    __shared__ int hcnt[BKT];
    int b = blockIdx.x, t = threadIdx.x;
    if (b < HIST_NB) {
        for (int i = t; i < BKT; i += 512) hcnt[i] = 0;
        __syncthreads();
#pragma unroll
        for (int q = 0; q < 8; q++) {
            int e = b * EPB + q * 512 + t;
            if (e < N_EDGES) atomicAdd(&hcnt[dst[e] >> 8], 1);
        }
        __syncthreads();
        for (int i = t; i < BKT; i += 512) histT[i * HIST_NB + b] = hcnt[i];
    } else {
        int idx = ((b - HIST_NB) * 512 + t) * 8;   // WT[c][k] = bf16(W[k][c])
        int c = idx >> 8, k0 = idx & 255;
        unsigned int uu[4];
#pragma unroll
        for (int q = 0; q < 4; q++) {
            float lo = W[(size_t)(k0 + 2 * q) * OUT_DIM + c];
            float hi = W[(size_t)(k0 + 2 * q + 1) * OUT_DIM + c];
            uu[q] = pack2bf(lo, hi);
        }
        *(uint4*)(WT + idx) = make_uint4(uu[0], uu[1], uu[2], uu[3]);
    }
}

// ---------------- L1: GEMM (32KB LDS, two-phase B) | scatter into bucketed tmp ----------------
// Scatter blocks self-compute prefixes from histT (work hides under concurrent
// GEMM blocks); block 0 publishes bstart/bcnt so bucket_sort needn't recompute.
__global__ __launch_bounds__(512) void gemm_scatter(const float* __restrict__ h,
                                                    const unsigned short* __restrict__ WT,
                                                    const float* __restrict__ attn,
                                                    unsigned short* __restrict__ zb,
                                                    float* __restrict__ s1,
                                                    float* __restrict__ s2,
                                                    const int* __restrict__ src,
                                                    const int* __restrict__ dst,
                                                    const int* __restrict__ histT,
                                                    unsigned int* __restrict__ tmp,
                                                    int* __restrict__ bstart,
                                                    int* __restrict__ bcnt) {
    __shared__ char smem[32768];
    const int t = threadIdx.x;

    if (blockIdx.x >= GEMM_NB) {       // ---- scatter path (aliases smem) ----
        int m = blockIdx.x - GEMM_NB;
        int* sS      = (int*)smem;          // 256
        int* bbL     = sS + 256;            // BKT
        int* bstartL = bbL + BKT;           // BKT
        int* cur     = bstartL + BKT;       // BKT

        int tot = 0, bb = 0;
        if (t < BKT) {
            const int* row = histT + t * HIST_NB;
            for (int m2 = 0; m2 < BKT; m2++) {
                int v = row[m2];
                tot += v;
                bb += (m2 < m) ? v : 0;
            }
            bbL[t] = bb;
            cur[t] = 0;
        }
        int d0 = (t < BKT) ? tot : 0;
        if (t < 256) sS[t] = d0;
        __syncthreads();
        int v = d0;
        for (int ofs = 1; ofs < 256; ofs <<= 1) {
            int add = (t < 256 && t >= ofs) ? sS[t - ofs] : 0;
            __syncthreads();
            if (t < 256) { v += add; sS[t] = v; }
            __syncthreads();
        }
        if (t < BKT) {
            bstartL[t] = v - d0;
            if (m == 0) { bstart[t] = v - d0; bcnt[t] = tot; }
        }
        __syncthreads();

#pragma unroll
        for (int q = 0; q < 8; q++) {
            int e = m * EPB + q * 512 + t;
            if (e < N_EDGES) {
                int d = dst[e];
                int bkt = d >> 8;
                int r = atomicAdd(&cur[bkt], 1);
                tmp[bstartL[bkt] + bbL[bkt] + r] =
                    ((unsigned int)d << 16) | (unsigned int)src[e];
            }
        }
        return;
    }

    // ---- GEMM path (unchanged) ----
    const int lane = t & 63, w = t >> 6;
    const int row0 = blockIdx.x * 128;
    const int m16 = lane & 15, kb = lane >> 4;

    const int rA = row0 + w * 16 + m16;
    const float* hrow = h + (size_t)min(rA, N_NODES - 1) * IN_DIM + kb * 8;

    f32x4 acc[8];
#pragma unroll
    for (int ct = 0; ct < 8; ct++) acc[ct] = (f32x4){0.f, 0.f, 0.f, 0.f};

    float4 v0 = *(const float4*)(hrow);
    float4 v1 = *(const float4*)(hrow + 4);

#pragma unroll
    for (int half = 0; half < 2; half++) {
        if (half) __syncthreads();
#pragma unroll
        for (int q = 0; q < 4; q++) {
            int G = t * 4 + q;
            int cc = G >> 4, gs = G & 15;
            const uint4 v = *(const uint4*)(WT + (size_t)cc * IN_DIM + half * 128 + gs * 8);
            *(uint4*)(smem + cc * 256 + ((gs ^ (cc & 7)) * 16)) = v;
        }
        __syncthreads();
#pragma unroll
        for (int kcl = 0; kcl < 4; kcl++) {
            const float4 c0 = v0, c1 = v1;
            int nk = half * 4 + kcl + 1;
            if (nk < 8) {
                v0 = *(const float4*)(hrow + nk * 32);
                v1 = *(const float4*)(hrow + nk * 32 + 4);
            }
            short8 af;
            af[0] = (short)f2bf_rne(c0.x); af[1] = (short)f2bf_rne(c0.y);
            af[2] = (short)f2bf_rne(c0.z); af[3] = (short)f2bf_rne(c0.w);
            af[4] = (short)f2bf_rne(c1.x); af[5] = (short)f2bf_rne(c1.y);
            af[6] = (short)f2bf_rne(c1.z); af[7] = (short)f2bf_rne(c1.w);
            const char* bbase = smem + m16 * 256 + (((kcl * 4 + kb) ^ (m16 & 7)) * 16);
#pragma unroll
            for (int ct = 0; ct < 8; ct++) {
                const short8 bf = *(const short8*)(bbase + ct * 4096);
                acc[ct] = __builtin_amdgcn_mfma_f32_16x16x32_bf16(af, bf, acc[ct], 0, 0, 0);
            }
        }
    }

    float a1v[8], a2v[8];
#pragma unroll
    for (int ct = 0; ct < 8; ct++) {
        a1v[ct] = attn[ct * 16 + m16];
        a2v[ct] = attn[OUT_DIM + ct * 16 + m16];
    }
#pragma unroll
    for (int i = 0; i < 4; i++) {
        int rr = row0 + w * 16 + kb * 4 + i;
        float q1 = 0.f, q2 = 0.f;
#pragma unroll
        for (int ct = 0; ct < 8; ct++) {
            q1 += acc[ct][i] * a1v[ct];
            q2 += acc[ct][i] * a2v[ct];
        }
        q1 += __shfl_xor(q1, 1); q1 += __shfl_xor(q1, 2);
        q1 += __shfl_xor(q1, 4); q1 += __shfl_xor(q1, 8);
        q2 += __shfl_xor(q2, 1); q2 += __shfl_xor(q2, 2);
        q2 += __shfl_xor(q2, 4); q2 += __shfl_xor(q2, 8);
        if (m16 == 0 && rr < N_NODES) { s1[rr] = q1; s2[rr] = q2; }
        if (rr < N_NODES) {
#pragma unroll
            for (int ct = 0; ct < 8; ct++)
                zb[(size_t)rr * OUT_DIM + ct * 16 + m16] = f2bf_rne(acc[ct][i]);
        }
    }
}

// ---------------- L2: per-bucket counting sort -> srcs (u16) + offs2 ----------------
__global__ __launch_bounds__(512) void bucket_sort(const unsigned int* __restrict__ tmp,
                                                   const int* __restrict__ bstart,
                                                   const int* __restrict__ bcnt,
                                                   unsigned short* __restrict__ srcs,
                                                   int* __restrict__ offs2) {
    __shared__ int sS[256];
    __shared__ int cnt[256];
    __shared__ int cur[256];
    int t = threadIdx.x, b = blockIdx.x;

    const int myStart = bstart[b];
    const int myCount = bcnt[b];
    if (t < 256) cnt[t] = 0;
    __syncthreads();

    // sweep 1: per-node counts within bucket
    for (int i = t; i < myCount; i += 512)
        atomicAdd(&cnt[(tmp[myStart + i] >> 16) & 255], 1);
    __syncthreads();

    // exclusive scan of cnt[256]
    int c0 = 0;
    if (t < 256) { c0 = cnt[t]; sS[t] = c0; }
    __syncthreads();
    int cv = c0;
    for (int ofs = 1; ofs < 256; ofs <<= 1) {
        int add = (t < 256 && t >= ofs) ? sS[t - ofs] : 0;
        __syncthreads();
        if (t < 256) { cv += add; sS[t] = cv; }
        __syncthreads();
    }
    if (t < 256) {
        int excl = cv - c0;
        int node = b * 256 + t;
        if (node < N_NODES) offs2[node] = myStart + excl;
        cur[t] = excl;
    }
    if (b == 0 && t == 0) offs2[N_NODES] = N_EDGES;
    __syncthreads();

    // sweep 2: place src payloads
    for (int i = t; i < myCount; i += 512) {
        unsigned int u = tmp[myStart + i];
        int r = atomicAdd(&cur[(u >> 16) & 255], 1);
        srcs[myStart + r] = (unsigned short)(u & 0xFFFFu);
    }
}

// ---------------- L3: softmax + gather-sum (lane = feature-pair, readlane bcast) ----------------
__global__ __launch_bounds__(256) void aggregate(const unsigned short* __restrict__ zb,
                                                 const int* __restrict__ offs2,
                                                 const unsigned short* __restrict__ srcs,
                                                 const float* __restrict__ s1,
                                                 const float* __restrict__ s2,
                                                 float* __restrict__ out) {
    int wid = (blockIdx.x * blockDim.x + threadIdx.x) >> 6;
    int lane = threadIdx.x & 63;
    if (wid >= N_NODES) return;
    float2* outp = (float2*)(out + (size_t)wid * OUT_DIM) + lane;

    int base = offs2[wid];
    int len = offs2[wid + 1] - base;
    if (len == 0) {
        *outp = make_float2(0.f, 0.f);
        return;
    }
    const float s2v = s2[wid];
    const unsigned int voff = lane * 2;      // ushort offset within a z row

    float sum = 0.f;
    float ax = 0.f, ay = 0.f;

    for (int c0 = 0; c0 < len; c0 += 64) {
        int i = c0 + lane;
        float ex = 0.f;
        int sj = 0;
        if (i < len) {
            sj = srcs[base + i];
            float lg = s1[sj] + s2v;
            lg = (lg >= 0.f) ? lg : ALPHA * lg;
            ex = __expf(lg);
        }
        sum += ex;
        int cnt = min(64, len - c0);
        int j = 0;
        for (; j + 4 <= cnt; j += 4) {
#pragma unroll
            for (int q = 0; q < 4; q++) {
                int s = __builtin_amdgcn_readlane(sj, j + q);
                float wj = __int_as_float(__builtin_amdgcn_readlane(__float_as_int(ex), j + q));
                unsigned int u = *(const unsigned int*)(zb + (size_t)(unsigned)s * OUT_DIM + voff);
                ax += wj * __uint_as_float(u << 16);
                ay += wj * __uint_as_float(u & 0xFFFF0000u);
            }
        }
        for (; j < cnt; j++) {
            int s = __builtin_amdgcn_readlane(sj, j);
            float wj = __int_as_float(__builtin_amdgcn_readlane(__float_as_int(ex), j));
            unsigned int u = *(const unsigned int*)(zb + (size_t)(unsigned)s * OUT_DIM + voff);
            ax += wj * __uint_as_float(u << 16);
            ay += wj * __uint_as_float(u & 0xFFFF0000u);
        }
    }
#pragma unroll
    for (int m = 32; m >= 1; m >>= 1) sum += __shfl_xor(sum, m);
    float inv = (sum > 0.f) ? 1.f / sum : 1.f;

    float a0 = ax * inv, a1 = ay * inv;
    float2 o;
    o.x = (a0 > 0.f) ? a0 : expm1f(a0);
    o.y = (a1 > 0.f) ? a1 : expm1f(a1);
    *outp = o;
}

// ---------------- launcher ----------------
extern "C" void kernel_launch(void* const* d_in, const int* in_sizes, int n_in,
                              void* d_out, int out_size, void* d_ws, size_t ws_size,
                              hipStream_t stream) {
    const float* h      = (const float*)d_in[0];
    const int*   src    = (const int*)d_in[1];
    const int*   dst    = (const int*)d_in[2];
    const float* W_fc   = (const float*)d_in[3];
    const float* attn_w = (const float*)d_in[4];
    float* out = (float*)d_out;

    char* ws = (char*)d_ws;
    unsigned short* zb = (unsigned short*)(ws + OFF_ZB);
    float* s1       = (float*)(ws + OFF_S1);
    float* s2       = (float*)(ws + OFF_S2);
    int*   offs2    = (int*)(ws + OFF_OFFS2);
    unsigned short* WT = (unsigned short*)(ws + OFF_WT);
    int*   histT    = (int*)(ws + OFF_HIST);
    int*   bstart   = (int*)(ws + OFF_BSTART);
    int*   bcnt     = (int*)(ws + OFF_BCNT);
    unsigned int* tmp = (unsigned int*)(ws + OFF_TMP);
    unsigned short* srcs = (unsigned short*)(ws + OFF_SRCS);

    hist_wt<<<HIST_NB + WT_NB, 512, 0, stream>>>(dst, W_fc, histT, WT);
    gemm_scatter<<<GEMM_NB + HIST_NB, 512, 0, stream>>>(h, WT, attn_w, zb, s1, s2,
                                                        src, dst, histT, tmp, bstart, bcnt);
    bucket_sort<<<BKT, 512, 0, stream>>>(tmp, bstart, bcnt, srcs, offs2);
    aggregate<<<(N_NODES * 64) / 256, 256, 0, stream>>>(zb, offs2, srcs, s1, s2, out);
}

// Round 17
// 76.231 us; speedup vs baseline: 1.1298x; 1.0127x over previous
//
#include <hip/hip_runtime.h>
#include <math.h>

#define N_NODES 50000
#define N_EDGES 800000
#define IN_DIM 256
#define OUT_DIM 128
#define ALPHA 0.2f

#define BKT 196              // coarse buckets: dst>>8
#define EPB 4096             // edges per hist/scatter block (512 thr * 8)
#define HIST_NB 196          // 196*4096 >= 800000
#define WT_NB   8            // 8*512*8 u16 = 32768
#define GEMM_NB 391          // ceil(50000/128), 8 waves, 16 rows/wave

typedef __attribute__((ext_vector_type(8))) short short8;
typedef __attribute__((ext_vector_type(4))) float f32x4;

// ---------------- workspace layout (bytes) ----------------
#define OFF_ZB     0u          // z bf16: 12,800,000
#define OFF_S1     12800000u
#define OFF_S2     13000000u
#define OFF_OFFS2  13200000u   // 50001 ints
#define OFF_WT     13400064u   // 65,536
#define OFF_HIST   13465600u   // histT[bkt][block]: 196*196*4 = 153,664
#define OFF_BBT    13619264u   // bbaseT[bkt][block]: 153,664
#define OFF_BTOT   13772928u   // 196*4 (pad 1024)
#define OFF_TMP    13773952u   // u32 packed edges: 3,200,000
#define OFF_SRCS   16973952u   // u16: 1,600,000
// total ~18.6 MB

static __device__ __forceinline__ unsigned short f2bf_rne(float f) {
    unsigned int u = __float_as_uint(f);
    unsigned int r = (u + 0x7FFFu + ((u >> 16) & 1u)) >> 16;
    return (unsigned short)r;
}
static __device__ __forceinline__ unsigned int pack2bf(float lo, float hi) {
    return (unsigned int)f2bf_rne(lo) | ((unsigned int)f2bf_rne(hi) << 16);
}

// ---------------- L0: bucket histogram | WT transpose ----------------
__global__ __launch_bounds__(512) void hist_wt(const int* __restrict__ dst,
                                               const float* __restrict__ W,
                                               int* __restrict__ histT,
                                               unsigned short* __restrict__ WT) {
    __shared__ int hcnt[BKT];
    int b = blockIdx.x, t = threadIdx.x;
    if (b < HIST_NB) {
        for (int i = t; i < BKT; i += 512) hcnt[i] = 0;
        __syncthreads();
#pragma unroll
        for (int q = 0; q < 8; q++) {
            int e = b * EPB + q * 512 + t;
            if (e < N_EDGES) atomicAdd(&hcnt[dst[e] >> 8], 1);
        }
        __syncthreads();
        for (int i = t; i < BKT; i += 512) histT[i * HIST_NB + b] = hcnt[i];
    } else {
        int idx = ((b - HIST_NB) * 512 + t) * 8;   // WT[c][k] = bf16(W[k][c])
        int c = idx >> 8, k0 = idx & 255;
        unsigned int uu[4];
#pragma unroll
        for (int q = 0; q < 4; q++) {
            float lo = W[(size_t)(k0 + 2 * q) * OUT_DIM + c];
            float hi = W[(size_t)(k0 + 2 * q + 1) * OUT_DIM + c];
            uu[q] = pack2bf(lo, hi);
        }
        *(uint4*)(WT + idx) = make_uint4(uu[0], uu[1], uu[2], uu[3]);
    }
}

// ---------------- L0.5: per-bucket scan over blocks -> bbaseT, btot ----------------
// R16 lesson: 196 scatter blocks each re-ran a 196-iter serial prefix (~16us
// latency-exposed). Compute it ONCE here (coalesced row scan, ~1.5us).
__global__ __launch_bounds__(256) void colscan(const int* __restrict__ histT,
                                               int* __restrict__ bbaseT,
                                               int* __restrict__ btot) {
    __shared__ int s[256];
    int t = threadIdx.x, b = blockIdx.x;
    int d0 = (t < HIST_NB) ? histT[b * HIST_NB + t] : 0;
    s[t] = d0;
    __syncthreads();
    int v = d0;
    for (int ofs = 1; ofs < 256; ofs <<= 1) {
        int add = (t >= ofs) ? s[t - ofs] : 0;
        __syncthreads();
        v += add;
        s[t] = v;
        __syncthreads();
    }
    if (t < HIST_NB) bbaseT[b * HIST_NB + t] = v - d0;   // excl. prefix over blocks
    if (t == HIST_NB - 1) btot[b] = v;                   // bucket total
}

// ---------------- L1: GEMM (32KB LDS, two-phase B) | scatter into bucketed tmp ----------------
__global__ __launch_bounds__(512) void gemm_scatter(const float* __restrict__ h,
                                                    const unsigned short* __restrict__ WT,
                                                    const float* __restrict__ attn,
                                                    unsigned short* __restrict__ zb,
                                                    float* __restrict__ s1,
                                                    float* __restrict__ s2,
                                                    const int* __restrict__ src,
                                                    const int* __restrict__ dst,
                                                    const int* __restrict__ bbaseT,
                                                    const int* __restrict__ btot,
                                                    unsigned int* __restrict__ tmp) {
    __shared__ char smem[32768];
    const int t = threadIdx.x;

    if (blockIdx.x >= GEMM_NB) {       // ---- scatter path (aliases smem) ----
        int m = blockIdx.x - GEMM_NB;
        int* sS      = (int*)smem;          // 256
        int* bbL     = sS + 256;            // BKT
        int* bstartL = bbL + BKT;           // BKT
        int* cur     = bstartL + BKT;       // BKT

        if (t < BKT) { bbL[t] = bbaseT[t * HIST_NB + m]; cur[t] = 0; }
        int d0 = (t < BKT) ? btot[t] : 0;
        if (t < 256) sS[t] = d0;
        __syncthreads();
        int v = d0;
        for (int ofs = 1; ofs < 256; ofs <<= 1) {
            int add = (t < 256 && t >= ofs) ? sS[t - ofs] : 0;
            __syncthreads();
            if (t < 256) { v += add; sS[t] = v; }
            __syncthreads();
        }
        if (t < BKT) bstartL[t] = v - d0;
        __syncthreads();

#pragma unroll
        for (int q = 0; q < 8; q++) {
            int e = m * EPB + q * 512 + t;
            if (e < N_EDGES) {
                int d = dst[e];
                int bkt = d >> 8;
                int r = atomicAdd(&cur[bkt], 1);
                tmp[bstartL[bkt] + bbL[bkt] + r] =
                    ((unsigned int)d << 16) | (unsigned int)src[e];
            }
        }
        return;
    }

    // ---- GEMM path (unchanged) ----
    const int lane = t & 63, w = t >> 6;
    const int row0 = blockIdx.x * 128;
    const int m16 = lane & 15, kb = lane >> 4;

    const int rA = row0 + w * 16 + m16;
    const float* hrow = h + (size_t)min(rA, N_NODES - 1) * IN_DIM + kb * 8;

    f32x4 acc[8];
#pragma unroll
    for (int ct = 0; ct < 8; ct++) acc[ct] = (f32x4){0.f, 0.f, 0.f, 0.f};

    float4 v0 = *(const float4*)(hrow);
    float4 v1 = *(const float4*)(hrow + 4);

#pragma unroll
    for (int half = 0; half < 2; half++) {
        if (half) __syncthreads();
#pragma unroll
        for (int q = 0; q < 4; q++) {
            int G = t * 4 + q;
            int cc = G >> 4, gs = G & 15;
            const uint4 v = *(const uint4*)(WT + (size_t)cc * IN_DIM + half * 128 + gs * 8);
            *(uint4*)(smem + cc * 256 + ((gs ^ (cc & 7)) * 16)) = v;
        }
        __syncthreads();
#pragma unroll
        for (int kcl = 0; kcl < 4; kcl++) {
            const float4 c0 = v0, c1 = v1;
            int nk = half * 4 + kcl + 1;
            if (nk < 8) {
                v0 = *(const float4*)(hrow + nk * 32);
                v1 = *(const float4*)(hrow + nk * 32 + 4);
            }
            short8 af;
            af[0] = (short)f2bf_rne(c0.x); af[1] = (short)f2bf_rne(c0.y);
            af[2] = (short)f2bf_rne(c0.z); af[3] = (short)f2bf_rne(c0.w);
            af[4] = (short)f2bf_rne(c1.x); af[5] = (short)f2bf_rne(c1.y);
            af[6] = (short)f2bf_rne(c1.z); af[7] = (short)f2bf_rne(c1.w);
            const char* bbase = smem + m16 * 256 + (((kcl * 4 + kb) ^ (m16 & 7)) * 16);
#pragma unroll
            for (int ct = 0; ct < 8; ct++) {
                const short8 bf = *(const short8*)(bbase + ct * 4096);
                acc[ct] = __builtin_amdgcn_mfma_f32_16x16x32_bf16(af, bf, acc[ct], 0, 0, 0);
            }
        }
    }

    float a1v[8], a2v[8];
#pragma unroll
    for (int ct = 0; ct < 8; ct++) {
        a1v[ct] = attn[ct * 16 + m16];
        a2v[ct] = attn[OUT_DIM + ct * 16 + m16];
    }
#pragma unroll
    for (int i = 0; i < 4; i++) {
        int rr = row0 + w * 16 + kb * 4 + i;
        float q1 = 0.f, q2 = 0.f;
#pragma unroll
        for (int ct = 0; ct < 8; ct++) {
            q1 += acc[ct][i] * a1v[ct];
            q2 += acc[ct][i] * a2v[ct];
        }
        q1 += __shfl_xor(q1, 1); q1 += __shfl_xor(q1, 2);
        q1 += __shfl_xor(q1, 4); q1 += __shfl_xor(q1, 8);
        q2 += __shfl_xor(q2, 1); q2 += __shfl_xor(q2, 2);
        q2 += __shfl_xor(q2, 4); q2 += __shfl_xor(q2, 8);
        if (m16 == 0 && rr < N_NODES) { s1[rr] = q1; s2[rr] = q2; }
        if (rr < N_NODES) {
#pragma unroll
            for (int ct = 0; ct < 8; ct++)
                zb[(size_t)rr * OUT_DIM + ct * 16 + m16] = f2bf_rne(acc[ct][i]);
        }
    }
}

// ---------------- L2: per-bucket counting sort -> srcs (u16) + offs2 ----------------
__global__ __launch_bounds__(512) void bucket_sort(const unsigned int* __restrict__ tmp,
                                                   const int* __restrict__ btot,
                                                   unsigned short* __restrict__ srcs,
                                                   int* __restrict__ offs2) {
    __shared__ int sS[256];
    __shared__ int cnt[256];
    __shared__ int cur[256];
    __shared__ int msS, mcS;
    int t = threadIdx.x, b = blockIdx.x;

    int d0 = (t < BKT) ? btot[t] : 0;
    if (t < 256) { sS[t] = d0; cnt[t] = 0; }
    __syncthreads();
    int v = d0;
    for (int ofs = 1; ofs < 256; ofs <<= 1) {
        int add = (t < 256 && t >= ofs) ? sS[t - ofs] : 0;
        __syncthreads();
        if (t < 256) { v += add; sS[t] = v; }
        __syncthreads();
    }
    if (t == b) { msS = v - d0; mcS = d0; }
    __syncthreads();
    const int myStart = msS, myCount = mcS;

    // sweep 1: per-node counts within bucket
    for (int i = t; i < myCount; i += 512)
        atomicAdd(&cnt[(tmp[myStart + i] >> 16) & 255], 1);
    __syncthreads();

    // exclusive scan of cnt[256]
    int c0 = 0;
    if (t < 256) { c0 = cnt[t]; sS[t] = c0; }
    __syncthreads();
    int cv = c0;
    for (int ofs = 1; ofs < 256; ofs <<= 1) {
        int add = (t < 256 && t >= ofs) ? sS[t - ofs] : 0;
        __syncthreads();
        if (t < 256) { cv += add; sS[t] = cv; }
        __syncthreads();
    }
    if (t < 256) {
        int excl = cv - c0;
        int node = b * 256 + t;
        if (node < N_NODES) offs2[node] = myStart + excl;
        cur[t] = excl;
    }
    if (b == 0 && t == 0) offs2[N_NODES] = N_EDGES;
    __syncthreads();

    // sweep 2: place src payloads
    for (int i = t; i < myCount; i += 512) {
        unsigned int u = tmp[myStart + i];
        int r = atomicAdd(&cur[(u >> 16) & 255], 1);
        srcs[myStart + r] = (unsigned short)(u & 0xFFFFu);
    }
}

// ---------------- L3: softmax + gather-sum (lane = feature-pair, readlane bcast) ----------------
__global__ __launch_bounds__(256) void aggregate(const unsigned short* __restrict__ zb,
                                                 const int* __restrict__ offs2,
                                                 const unsigned short* __restrict__ srcs,
                                                 const float* __restrict__ s1,
                                                 const float* __restrict__ s2,
                                                 float* __restrict__ out) {
    int wid = (blockIdx.x * blockDim.x + threadIdx.x) >> 6;
    int lane = threadIdx.x & 63;
    if (wid >= N_NODES) return;
    float2* outp = (float2*)(out + (size_t)wid * OUT_DIM) + lane;

    int base = offs2[wid];
    int len = offs2[wid + 1] - base;
    if (len == 0) {
        *outp = make_float2(0.f, 0.f);
        return;
    }
    const float s2v = s2[wid];
    const unsigned int voff = lane * 2;      // ushort offset within a z row

    float sum = 0.f;
    float ax = 0.f, ay = 0.f;

    for (int c0 = 0; c0 < len; c0 += 64) {
        int i = c0 + lane;
        float ex = 0.f;
        int sj = 0;
        if (i < len) {
            sj = srcs[base + i];
            float lg = s1[sj] + s2v;
            lg = (lg >= 0.f) ? lg : ALPHA * lg;
            ex = __expf(lg);
        }
        sum += ex;
        int cnt = min(64, len - c0);
        int j = 0;
        for (; j + 4 <= cnt; j += 4) {
#pragma unroll
            for (int q = 0; q < 4; q++) {
                int s = __builtin_amdgcn_readlane(sj, j + q);
                float wj = __int_as_float(__builtin_amdgcn_readlane(__float_as_int(ex), j + q));
                unsigned int u = *(const unsigned int*)(zb + (size_t)(unsigned)s * OUT_DIM + voff);
                ax += wj * __uint_as_float(u << 16);
                ay += wj * __uint_as_float(u & 0xFFFF0000u);
            }
        }
        for (; j < cnt; j++) {
            int s = __builtin_amdgcn_readlane(sj, j);
            float wj = __int_as_float(__builtin_amdgcn_readlane(__float_as_int(ex), j));
            unsigned int u = *(const unsigned int*)(zb + (size_t)(unsigned)s * OUT_DIM + voff);
            ax += wj * __uint_as_float(u << 16);
            ay += wj * __uint_as_float(u & 0xFFFF0000u);
        }
    }
#pragma unroll
    for (int m = 32; m >= 1; m >>= 1) sum += __shfl_xor(sum, m);
    float inv = (sum > 0.f) ? 1.f / sum : 1.f;

    float a0 = ax * inv, a1 = ay * inv;
    float2 o;
    o.x = (a0 > 0.f) ? a0 : expm1f(a0);
    o.y = (a1 > 0.f) ? a1 : expm1f(a1);
    *outp = o;
}

// ---------------- launcher ----------------
extern "C" void kernel_launch(void* const* d_in, const int* in_sizes, int n_in,
                              void* d_out, int out_size, void* d_ws, size_t ws_size,
                              hipStream_t stream) {
    const float* h      = (const float*)d_in[0];
    const int*   src    = (const int*)d_in[1];
    const int*   dst    = (const int*)d_in[2];
    const float* W_fc   = (const float*)d_in[3];
    const float* attn_w = (const float*)d_in[4];
    float* out = (float*)d_out;

    char* ws = (char*)d_ws;
    unsigned short* zb = (unsigned short*)(ws + OFF_ZB);
    float* s1       = (float*)(ws + OFF_S1);
    float* s2       = (float*)(ws + OFF_S2);
    int*   offs2    = (int*)(ws + OFF_OFFS2);
    unsigned short* WT = (unsigned short*)(ws + OFF_WT);
    int*   histT    = (int*)(ws + OFF_HIST);
    int*   bbaseT   = (int*)(ws + OFF_BBT);
    int*   btot     = (int*)(ws + OFF_BTOT);
    unsigned int* tmp = (unsigned int*)(ws + OFF_TMP);
    unsigned short* srcs = (unsigned short*)(ws + OFF_SRCS);

    hist_wt<<<HIST_NB + WT_NB, 512, 0, stream>>>(dst, W_fc, histT, WT);
    colscan<<<BKT, 256, 0, stream>>>(histT, bbaseT, btot);
    gemm_scatter<<<GEMM_NB + HIST_NB, 512, 0, stream>>>(h, WT, attn_w, zb, s1, s2,
                                                        src, dst, bbaseT, btot, tmp);
    bucket_sort<<<BKT, 512, 0, stream>>>(tmp, btot, srcs, offs2);
    aggregate<<<(N_NODES * 64) / 256, 256, 0, stream>>>(zb, offs2, srcs, s1, s2, out);
}

// Round 18
// 73.339 us; speedup vs baseline: 1.1743x; 1.0394x over previous
//
#include <hip/hip_runtime.h>
#include <math.h>

#define N_NODES 50000
#define N_EDGES 800000
#define IN_DIM 256
#define OUT_DIM 128
#define ALPHA 0.2f

#define BKT 196              // coarse buckets: dst>>8
#define EPB 4096             // edges per hist/scatter block (512 thr * 8)
#define HIST_NB 196          // 196*4096 >= 800000
#define WT_NB   8            // 8*512*8 u16 = 32768
#define GEMM_NB 391          // ceil(50000/128), 8 waves, 16 rows/wave

typedef __attribute__((ext_vector_type(8))) short short8;
typedef __attribute__((ext_vector_type(4))) float f32x4;

// ---------------- workspace layout (bytes) ----------------
#define OFF_ZB     0u          // z bf16: 12,800,000
#define OFF_S1     12800000u
#define OFF_S2     13000000u
#define OFF_OFFS2  13200000u   // 50001 ints
#define OFF_WT     13400064u   // 65,536
#define OFF_HIST   13465600u   // histT[bkt][block]: 196*196*4 = 153,664
#define OFF_BBT    13619264u   // bbaseT[bkt][block]: 153,664
#define OFF_BTOT   13772928u   // 196*4 (pad 1024)
#define OFF_TMP    13773952u   // u32 packed edges: 3,200,000
#define OFF_SRCS   16973952u   // u16: 1,600,000
// total ~18.6 MB

static __device__ __forceinline__ unsigned short f2bf_rne(float f) {
    unsigned int u = __float_as_uint(f);
    unsigned int r = (u + 0x7FFFu + ((u >> 16) & 1u)) >> 16;
    return (unsigned short)r;
}
static __device__ __forceinline__ unsigned int pack2bf(float lo, float hi) {
    return (unsigned int)f2bf_rne(lo) | ((unsigned int)f2bf_rne(hi) << 16);
}

// ---------------- L0: bucket histogram | WT transpose ----------------
__global__ __launch_bounds__(512) void hist_wt(const int* __restrict__ dst,
                                               const float* __restrict__ W,
                                               int* __restrict__ histT,
                                               unsigned short* __restrict__ WT) {
    __shared__ int hcnt[BKT];
    int b = blockIdx.x, t = threadIdx.x;
    if (b < HIST_NB) {
        for (int i = t; i < BKT; i += 512) hcnt[i] = 0;
        __syncthreads();
#pragma unroll
        for (int q = 0; q < 8; q++) {
            int e = b * EPB + q * 512 + t;
            if (e < N_EDGES) atomicAdd(&hcnt[dst[e] >> 8], 1);
        }
        __syncthreads();
        for (int i = t; i < BKT; i += 512) histT[i * HIST_NB + b] = hcnt[i];
    } else {
        int idx = ((b - HIST_NB) * 512 + t) * 8;   // WT[c][k] = bf16(W[k][c])
        int c = idx >> 8, k0 = idx & 255;
        unsigned int uu[4];
#pragma unroll
        for (int q = 0; q < 4; q++) {
            float lo = W[(size_t)(k0 + 2 * q) * OUT_DIM + c];
            float hi = W[(size_t)(k0 + 2 * q + 1) * OUT_DIM + c];
            uu[q] = pack2bf(lo, hi);
        }
        *(uint4*)(WT + idx) = make_uint4(uu[0], uu[1], uu[2], uu[3]);
    }
}

// ---------------- L0.5: per-bucket scan over blocks -> bbaseT, btot ----------------
__global__ __launch_bounds__(256) void colscan(const int* __restrict__ histT,
                                               int* __restrict__ bbaseT,
                                               int* __restrict__ btot) {
    __shared__ int s[256];
    int t = threadIdx.x, b = blockIdx.x;
    int d0 = (t < HIST_NB) ? histT[b * HIST_NB + t] : 0;
    s[t] = d0;
    __syncthreads();
    int v = d0;
    for (int ofs = 1; ofs < 256; ofs <<= 1) {
        int add = (t >= ofs) ? s[t - ofs] : 0;
        __syncthreads();
        v += add;
        s[t] = v;
        __syncthreads();
    }
    if (t < HIST_NB) bbaseT[b * HIST_NB + t] = v - d0;   // excl. prefix over blocks
    if (t == HIST_NB - 1) btot[b] = v;                   // bucket total
}

// ---------------- L1: GEMM (32KB LDS, two-phase B) | LDS-sorted coalesced scatter ----------------
// R17 lesson: 800K random 4B writes serialize like atomics (~1 line-op/cy/XCD).
// Scatter now counting-sorts its 4096 edges in LDS, then writes each bucket run
// as a CONTIGUOUS chunk -> ~10x fewer write transactions, single-owner lines.
__global__ __launch_bounds__(512) void gemm_scatter(const float* __restrict__ h,
                                                    const unsigned short* __restrict__ WT,
                                                    const float* __restrict__ attn,
                                                    unsigned short* __restrict__ zb,
                                                    float* __restrict__ s1,
                                                    float* __restrict__ s2,
                                                    const int* __restrict__ src,
                                                    const int* __restrict__ dst,
                                                    const int* __restrict__ bbaseT,
                                                    const int* __restrict__ btot,
                                                    unsigned int* __restrict__ tmp) {
    __shared__ char smem[32768];
    const int t = threadIdx.x;

    if (blockIdx.x >= GEMM_NB) {       // ---- scatter path (aliases smem) ----
        int m = blockIdx.x - GEMM_NB;
        int* sS       = (int*)smem;             // 256
        int* binStart = sS + 256;               // 256
        int* cur      = binStart + 256;         // 256
        int* bbL      = cur + 256;              // BKT
        int* bstartL  = bbL + BKT;              // BKT
        unsigned int* buf = (unsigned int*)(bstartL + BKT);   // 4096 u32 = 16KB

        const int nv = min(EPB, N_EDGES - m * EPB);   // valid edges this block

        if (t < 256) cur[t] = 0;
        if (t < BKT) bbL[t] = bbaseT[t * HIST_NB + m];
        __syncthreads();

        // load + pack + LDS count
        unsigned int u[8];
        int nq = 0;
#pragma unroll
        for (int q = 0; q < 8; q++) {
            int e = m * EPB + q * 512 + t;
            if (e < N_EDGES) {
                u[nq] = ((unsigned int)dst[e] << 16) | (unsigned int)src[e];
                atomicAdd(&cur[u[nq] >> 24], 1);
                nq++;
            }
        }
        __syncthreads();

        // scan 1: binStart = excl scan of per-bucket counts (256 wide)
        int c0 = (t < 256) ? cur[t] : 0;
        if (t < 256) sS[t] = c0;
        __syncthreads();
        int cv = c0;
        for (int ofs = 1; ofs < 256; ofs <<= 1) {
            int add = (t < 256 && t >= ofs) ? sS[t - ofs] : 0;
            __syncthreads();
            if (t < 256) { cv += add; sS[t] = cv; }
            __syncthreads();
        }
        if (t < 256) binStart[t] = cv - c0;
        __syncthreads();

        // scan 2: bstartL = excl scan of bucket totals (global)
        int d0 = (t < BKT) ? btot[t] : 0;
        if (t < 256) sS[t] = d0;
        if (t < 256) cur[t] = binStart[t];      // reset cursors to bin starts
        __syncthreads();
        int v = d0;
        for (int ofs = 1; ofs < 256; ofs <<= 1) {
            int add = (t < 256 && t >= ofs) ? sS[t - ofs] : 0;
            __syncthreads();
            if (t < 256) { v += add; sS[t] = v; }
            __syncthreads();
        }
        if (t < BKT) bstartL[t] = v - d0;
        __syncthreads();

        // place into sorted LDS buffer
        for (int q = 0; q < nq; q++) {
            int p = atomicAdd(&cur[u[q] >> 24], 1);
            buf[p] = u[q];
        }
        __syncthreads();

        // phase 2: coalesced run writes
        for (int j = t; j < nv; j += 512) {
            unsigned int w = buf[j];
            int bkt = w >> 24;
            tmp[bstartL[bkt] + bbL[bkt] + (j - binStart[bkt])] = w;
        }
        return;
    }

    // ---- GEMM path (unchanged) ----
    const int lane = t & 63, w = t >> 6;
    const int row0 = blockIdx.x * 128;
    const int m16 = lane & 15, kb = lane >> 4;

    const int rA = row0 + w * 16 + m16;
    const float* hrow = h + (size_t)min(rA, N_NODES - 1) * IN_DIM + kb * 8;

    f32x4 acc[8];
#pragma unroll
    for (int ct = 0; ct < 8; ct++) acc[ct] = (f32x4){0.f, 0.f, 0.f, 0.f};

    float4 v0 = *(const float4*)(hrow);
    float4 v1 = *(const float4*)(hrow + 4);

#pragma unroll
    for (int half = 0; half < 2; half++) {
        if (half) __syncthreads();
#pragma unroll
        for (int q = 0; q < 4; q++) {
            int G = t * 4 + q;
            int cc = G >> 4, gs = G & 15;
            const uint4 v = *(const uint4*)(WT + (size_t)cc * IN_DIM + half * 128 + gs * 8);
            *(uint4*)(smem + cc * 256 + ((gs ^ (cc & 7)) * 16)) = v;
        }
        __syncthreads();
#pragma unroll
        for (int kcl = 0; kcl < 4; kcl++) {
            const float4 c0 = v0, c1 = v1;
            int nk = half * 4 + kcl + 1;
            if (nk < 8) {
                v0 = *(const float4*)(hrow + nk * 32);
                v1 = *(const float4*)(hrow + nk * 32 + 4);
            }
            short8 af;
            af[0] = (short)f2bf_rne(c0.x); af[1] = (short)f2bf_rne(c0.y);
            af[2] = (short)f2bf_rne(c0.z); af[3] = (short)f2bf_rne(c0.w);
            af[4] = (short)f2bf_rne(c1.x); af[5] = (short)f2bf_rne(c1.y);
            af[6] = (short)f2bf_rne(c1.z); af[7] = (short)f2bf_rne(c1.w);
            const char* bbase = smem + m16 * 256 + (((kcl * 4 + kb) ^ (m16 & 7)) * 16);
#pragma unroll
            for (int ct = 0; ct < 8; ct++) {
                const short8 bf = *(const short8*)(bbase + ct * 4096);
                acc[ct] = __builtin_amdgcn_mfma_f32_16x16x32_bf16(af, bf, acc[ct], 0, 0, 0);
            }
        }
    }

    float a1v[8], a2v[8];
#pragma unroll
    for (int ct = 0; ct < 8; ct++) {
        a1v[ct] = attn[ct * 16 + m16];
        a2v[ct] = attn[OUT_DIM + ct * 16 + m16];
    }
#pragma unroll
    for (int i = 0; i < 4; i++) {
        int rr = row0 + w * 16 + kb * 4 + i;
        float q1 = 0.f, q2 = 0.f;
#pragma unroll
        for (int ct = 0; ct < 8; ct++) {
            q1 += acc[ct][i] * a1v[ct];
            q2 += acc[ct][i] * a2v[ct];
        }
        q1 += __shfl_xor(q1, 1); q1 += __shfl_xor(q1, 2);
        q1 += __shfl_xor(q1, 4); q1 += __shfl_xor(q1, 8);
        q2 += __shfl_xor(q2, 1); q2 += __shfl_xor(q2, 2);
        q2 += __shfl_xor(q2, 4); q2 += __shfl_xor(q2, 8);
        if (m16 == 0 && rr < N_NODES) { s1[rr] = q1; s2[rr] = q2; }
        if (rr < N_NODES) {
#pragma unroll
            for (int ct = 0; ct < 8; ct++)
                zb[(size_t)rr * OUT_DIM + ct * 16 + m16] = f2bf_rne(acc[ct][i]);
        }
    }
}

// ---------------- L2: per-bucket counting sort -> srcs (u16) + offs2 ----------------
__global__ __launch_bounds__(512) void bucket_sort(const unsigned int* __restrict__ tmp,
                                                   const int* __restrict__ btot,
                                                   unsigned short* __restrict__ srcs,
                                                   int* __restrict__ offs2) {
    __shared__ int sS[256];
    __shared__ int cnt[256];
    __shared__ int cur[256];
    __shared__ int msS, mcS;
    int t = threadIdx.x, b = blockIdx.x;

    int d0 = (t < BKT) ? btot[t] : 0;
    if (t < 256) { sS[t] = d0; cnt[t] = 0; }
    __syncthreads();
    int v = d0;
    for (int ofs = 1; ofs < 256; ofs <<= 1) {
        int add = (t < 256 && t >= ofs) ? sS[t - ofs] : 0;
        __syncthreads();
        if (t < 256) { v += add; sS[t] = v; }
        __syncthreads();
    }
    if (t == b) { msS = v - d0; mcS = d0; }
    __syncthreads();
    const int myStart = msS, myCount = mcS;

    // sweep 1: per-node counts within bucket
    for (int i = t; i < myCount; i += 512)
        atomicAdd(&cnt[(tmp[myStart + i] >> 16) & 255], 1);
    __syncthreads();

    // exclusive scan of cnt[256]
    int c0 = 0;
    if (t < 256) { c0 = cnt[t]; sS[t] = c0; }
    __syncthreads();
    int cv = c0;
    for (int ofs = 1; ofs < 256; ofs <<= 1) {
        int add = (t < 256 && t >= ofs) ? sS[t - ofs] : 0;
        __syncthreads();
        if (t < 256) { cv += add; sS[t] = cv; }
        __syncthreads();
    }
    if (t < 256) {
        int excl = cv - c0;
        int node = b * 256 + t;
        if (node < N_NODES) offs2[node] = myStart + excl;
        cur[t] = excl;
    }
    if (b == 0 && t == 0) offs2[N_NODES] = N_EDGES;
    __syncthreads();

    // sweep 2: place src payloads
    for (int i = t; i < myCount; i += 512) {
        unsigned int u = tmp[myStart + i];
        int r = atomicAdd(&cur[(u >> 16) & 255], 1);
        srcs[myStart + r] = (unsigned short)(u & 0xFFFFu);
    }
}

// ---------------- L3: softmax + gather-sum (lane = feature-pair, readlane bcast) ----------------
__global__ __launch_bounds__(256) void aggregate(const unsigned short* __restrict__ zb,
                                                 const int* __restrict__ offs2,
                                                 const unsigned short* __restrict__ srcs,
                                                 const float* __restrict__ s1,
                                                 const float* __restrict__ s2,
                                                 float* __restrict__ out) {
    int wid = (blockIdx.x * blockDim.x + threadIdx.x) >> 6;
    int lane = threadIdx.x & 63;
    if (wid >= N_NODES) return;
    float2* outp = (float2*)(out + (size_t)wid * OUT_DIM) + lane;

    int base = offs2[wid];
    int len = offs2[wid + 1] - base;
    if (len == 0) {
        *outp = make_float2(0.f, 0.f);
        return;
    }
    const float s2v = s2[wid];
    const unsigned int voff = lane * 2;      // ushort offset within a z row

    float sum = 0.f;
    float ax = 0.f, ay = 0.f;

    for (int c0 = 0; c0 < len; c0 += 64) {
        int i = c0 + lane;
        float ex = 0.f;
        int sj = 0;
        if (i < len) {
            sj = srcs[base + i];
            float lg = s1[sj] + s2v;
            lg = (lg >= 0.f) ? lg : ALPHA * lg;
            ex = __expf(lg);
        }
        sum += ex;
        int cnt = min(64, len - c0);
        int j = 0;
        for (; j + 4 <= cnt; j += 4) {
#pragma unroll
            for (int q = 0; q < 4; q++) {
                int s = __builtin_amdgcn_readlane(sj, j + q);
                float wj = __int_as_float(__builtin_amdgcn_readlane(__float_as_int(ex), j + q));
                unsigned int u = *(const unsigned int*)(zb + (size_t)(unsigned)s * OUT_DIM + voff);
                ax += wj * __uint_as_float(u << 16);
                ay += wj * __uint_as_float(u & 0xFFFF0000u);
            }
        }
        for (; j < cnt; j++) {
            int s = __builtin_amdgcn_readlane(sj, j);
            float wj = __int_as_float(__builtin_amdgcn_readlane(__float_as_int(ex), j));
            unsigned int u = *(const unsigned int*)(zb + (size_t)(unsigned)s * OUT_DIM + voff);
            ax += wj * __uint_as_float(u << 16);
            ay += wj * __uint_as_float(u & 0xFFFF0000u);
        }
    }
#pragma unroll
    for (int m = 32; m >= 1; m >>= 1) sum += __shfl_xor(sum, m);
    float inv = (sum > 0.f) ? 1.f / sum : 1.f;

    float a0 = ax * inv, a1 = ay * inv;
    float2 o;
    o.x = (a0 > 0.f) ? a0 : expm1f(a0);
    o.y = (a1 > 0.f) ? a1 : expm1f(a1);
    *outp = o;
}

// ---------------- launcher ----------------
extern "C" void kernel_launch(void* const* d_in, const int* in_sizes, int n_in,
                              void* d_out, int out_size, void* d_ws, size_t ws_size,
                              hipStream_t stream) {
    const float* h      = (const float*)d_in[0];
    const int*   src    = (const int*)d_in[1];
    const int*   dst    = (const int*)d_in[2];
    const float* W_fc   = (const float*)d_in[3];
    const float* attn_w = (const float*)d_in[4];
    float* out = (float*)d_out;

    char* ws = (char*)d_ws;
    unsigned short* zb = (unsigned short*)(ws + OFF_ZB);
    float* s1       = (float*)(ws + OFF_S1);
    float* s2       = (float*)(ws + OFF_S2);
    int*   offs2    = (int*)(ws + OFF_OFFS2);
    unsigned short* WT = (unsigned short*)(ws + OFF_WT);
    int*   histT    = (int*)(ws + OFF_HIST);
    int*   bbaseT   = (int*)(ws + OFF_BBT);
    int*   btot     = (int*)(ws + OFF_BTOT);
    unsigned int* tmp = (unsigned int*)(ws + OFF_TMP);
    unsigned short* srcs = (unsigned short*)(ws + OFF_SRCS);

    hist_wt<<<HIST_NB + WT_NB, 512, 0, stream>>>(dst, W_fc, histT, WT);
    colscan<<<BKT, 256, 0, stream>>>(histT, bbaseT, btot);
    gemm_scatter<<<GEMM_NB + HIST_NB, 512, 0, stream>>>(h, WT, attn_w, zb, s1, s2,
                                                        src, dst, bbaseT, btot, tmp);
    bucket_sort<<<BKT, 512, 0, stream>>>(tmp, btot, srcs, offs2);
    aggregate<<<(N_NODES * 64) / 256, 256, 0, stream>>>(zb, offs2, srcs, s1, s2, out);
}